// Round 3
// baseline (871.547 us; speedup 1.0000x reference)
//
#include <hip/hip_runtime.h>

#define N_D 64
#define PBITS 7
#define PSZ 128  // nodes per partition; P = ceil(N/128) = 782 for N=100000

// ---------------- zero partition counters ----------------
__global__ __launch_bounds__(256) void zero_kernel(int* __restrict__ cntD,
                                                   int* __restrict__ cntS, int P) {
    int i = blockIdx.x * 256 + threadIdx.x;
    if (i < P) { cntD[i] = 0; cntS[i] = 0; }
}

// ---------------- coarse histogram by partition (dst and src) ----------------
__global__ __launch_bounds__(256) void coarse_hist_kernel(const int* __restrict__ src,
                                                          const int* __restrict__ dst,
                                                          int* __restrict__ cntD,
                                                          int* __restrict__ cntS,
                                                          int E, int P) {
    extern __shared__ int sh[];  // 2*P ints
    int* hD = sh;
    int* hS = sh + P;
    int t = threadIdx.x;
    for (int i = t; i < 2 * P; i += 256) sh[i] = 0;
    __syncthreads();
    int per = (E + gridDim.x - 1) / gridDim.x;
    int beg = blockIdx.x * per, end = min(E, beg + per);
    for (int e = beg + t; e < end; e += 256) {
        atomicAdd(&hD[dst[e] >> PBITS], 1);
        atomicAdd(&hS[src[e] >> PBITS], 1);
    }
    __syncthreads();
    for (int p = t; p < P; p += 256) {
        if (hD[p]) atomicAdd(&cntD[p], hD[p]);
        if (hS[p]) atomicAdd(&cntS[p], hS[p]);
    }
}

// ---------------- parallel scan over P partials (both arrays), 1 block ----------------
__global__ __launch_bounds__(1024) void scan_kernel(const int* __restrict__ cntD,
                                                    const int* __restrict__ cntS,
                                                    int* __restrict__ startD,
                                                    int* __restrict__ cursorD,
                                                    int* __restrict__ startS,
                                                    int* __restrict__ cursorS, int P) {
    __shared__ int s[1024];
    int t = threadIdx.x;
    // ---- scan D ----
    int v = (t < P) ? cntD[t] : 0;
    s[t] = v;
    __syncthreads();
    for (int off = 1; off < 1024; off <<= 1) {
        int x = (t >= off) ? s[t - off] : 0;
        __syncthreads();
        s[t] += x;
        __syncthreads();
    }
    if (t < P) { int ex = s[t] - v; startD[t] = ex; cursorD[t] = ex; }
    if (t == 1023) startD[P] = s[1023];
    __syncthreads();
    // ---- scan S ----
    v = (t < P) ? cntS[t] : 0;
    s[t] = v;
    __syncthreads();
    for (int off = 1; off < 1024; off <<= 1) {
        int x = (t >= off) ? s[t - off] : 0;
        __syncthreads();
        s[t] += x;
        __syncthreads();
    }
    if (t < P) { int ex = s[t] - v; startS[t] = ex; cursorS[t] = ex; }
    if (t == 1023) startS[P] = s[1023];
}

// ---------------- scatter edges into partition ranges ----------------
// epart entry: (src << 7) | (dst & 127)   (src < 2^17 on this problem)
// spart entry: (uchar)(src & 127)
__global__ __launch_bounds__(256) void coarse_scatter_kernel(const int* __restrict__ src,
                                                             const int* __restrict__ dst,
                                                             int* __restrict__ cursorD,
                                                             int* __restrict__ cursorS,
                                                             unsigned* __restrict__ epart,
                                                             unsigned char* __restrict__ spart,
                                                             int E, int P) {
    extern __shared__ int sh[];  // 4*P ints: hD, hS, bD, bS
    int* hD = sh;
    int* hS = sh + P;
    int* bD = sh + 2 * P;
    int* bS = sh + 3 * P;
    int t = threadIdx.x;
    for (int i = t; i < 2 * P; i += 256) sh[i] = 0;
    __syncthreads();
    int per = (E + gridDim.x - 1) / gridDim.x;
    int beg = blockIdx.x * per, end = min(E, beg + per);
    // pass 1: local histograms
    for (int e = beg + t; e < end; e += 256) {
        atomicAdd(&hD[dst[e] >> PBITS], 1);
        atomicAdd(&hS[src[e] >> PBITS], 1);
    }
    __syncthreads();
    // reserve contiguous chunks per (block, partition); reset local cursors
    for (int p = t; p < P; p += 256) {
        int hd = hD[p];
        if (hd) bD[p] = atomicAdd(&cursorD[p], hd);
        hD[p] = 0;
        int hs_ = hS[p];
        if (hs_) bS[p] = atomicAdd(&cursorS[p], hs_);
        hS[p] = 0;
    }
    __syncthreads();
    // pass 2: place edges
    for (int e = beg + t; e < end; e += 256) {
        int d = dst[e], s0 = src[e];
        int pd = d >> PBITS, ps = s0 >> PBITS;
        int od = atomicAdd(&hD[pd], 1);
        epart[bD[pd] + od] = ((unsigned)s0 << PBITS) | (unsigned)(d & (PSZ - 1));
        int os = atomicAdd(&hS[ps], 1);
        spart[bS[ps] + os] = (unsigned char)(s0 & (PSZ - 1));
    }
}

// ---------------- per-partition out-degree histogram -> dis = rsqrt(deg+1) ----------------
__global__ __launch_bounds__(256) void outdeg_dis_kernel(const unsigned char* __restrict__ spart,
                                                         const int* __restrict__ startS,
                                                         float* __restrict__ dis, int N) {
    __shared__ int hist[PSZ];
    int p = blockIdx.x, t = threadIdx.x;
    if (t < PSZ) hist[t] = 0;
    __syncthreads();
    int beg = startS[p], end = startS[p + 1];
    for (int i = beg + t; i < end; i += 256) atomicAdd(&hist[spart[i]], 1);
    __syncthreads();
    if (t < PSZ) {
        int node = p * PSZ + t;
        if (node < N) dis[node] = rsqrtf((float)(hist[t] + 1));
    }
}

// ---------------- hs = dis * (x @ W^T + b) ----------------
#define ROWS_PB 32
__global__ __launch_bounds__(256) void linear_kernel(const float* __restrict__ x,
                                                     const float* __restrict__ W,
                                                     const float* __restrict__ b,
                                                     const float* __restrict__ dis,
                                                     float* __restrict__ hs, int N) {
    __shared__ float Ws[N_D][N_D + 1];
    __shared__ float bs[N_D];
    __shared__ float xs[ROWS_PB][N_D];

    int tid = threadIdx.x;
    for (int i = tid; i < N_D * N_D; i += 256)
        Ws[i >> 6][i & 63] = W[i];
    if (tid < N_D) bs[tid] = b[tid];

    int row0 = blockIdx.x * ROWS_PB;
    const float4* x4 = (const float4*)(x + (size_t)row0 * N_D);
    float4* xs4 = (float4*)&xs[0][0];
    const int n4 = ROWS_PB * N_D / 4;  // 512 float4s
    if (row0 + ROWS_PB <= N) {
        for (int i = tid; i < n4; i += 256) xs4[i] = x4[i];
    } else {
        for (int i = tid; i < n4; i += 256) {
            int row = row0 + (i >> 4);
            float4 v = make_float4(0.f, 0.f, 0.f, 0.f);
            if (row < N) v = x4[i];
            xs4[i] = v;
        }
    }
    __syncthreads();

    int o = tid & 63;
    int r0 = tid >> 6;
    float acc[ROWS_PB / 4];
#pragma unroll
    for (int j = 0; j < ROWS_PB / 4; j++) acc[j] = 0.f;

#pragma unroll 8
    for (int k = 0; k < N_D; k++) {
        float w = Ws[o][k];
#pragma unroll
        for (int j = 0; j < ROWS_PB / 4; j++)
            acc[j] += xs[r0 + 4 * j][k] * w;
    }

#pragma unroll
    for (int j = 0; j < ROWS_PB / 4; j++) {
        int row = row0 + r0 + 4 * j;
        if (row < N) hs[(size_t)row * N_D + o] = (acc[j] + bs[o]) * dis[row];
    }
}

// ---------------- partition gather: LDS accumulator, one block per partition ----------------
// out[i] = dis[i] * (hs[i] + sum_in hs[src]) / (indeg[i]+1)
__global__ __launch_bounds__(256) void partition_gather_kernel(const unsigned* __restrict__ epart,
                                                               const int* __restrict__ startD,
                                                               const float* __restrict__ hs,
                                                               const float* __restrict__ dis,
                                                               float* __restrict__ out, int N) {
    __shared__ float acc[PSZ][N_D];  // 32 KB
    __shared__ int indeg[PSZ];
    __shared__ unsigned ebuf[256];
    int p = blockIdx.x, t = threadIdx.x;
    int w = t >> 6, lane = t & 63;

    for (int i = t; i < PSZ * N_D; i += 256) ((float*)acc)[i] = 0.f;
    if (t < PSZ) indeg[t] = 0;

    int beg = startD[p], end = startD[p + 1];
    for (int base = beg; base < end; base += 256) {
        int nb = min(256, end - base);
        __syncthreads();
        if (t < nb) {
            unsigned e = epart[base + t];
            ebuf[t] = e;
            atomicAdd(&indeg[e & (PSZ - 1)], 1);
        }
        __syncthreads();
        int lo = w * 64, hi = min(nb, lo + 64);
        int i = lo;
        for (; i + 4 <= hi; i += 4) {
            unsigned e0 = ebuf[i], e1 = ebuf[i + 1], e2 = ebuf[i + 2], e3 = ebuf[i + 3];
            float v0 = hs[(size_t)(e0 >> PBITS) * N_D + lane];
            float v1 = hs[(size_t)(e1 >> PBITS) * N_D + lane];
            float v2 = hs[(size_t)(e2 >> PBITS) * N_D + lane];
            float v3 = hs[(size_t)(e3 >> PBITS) * N_D + lane];
            atomicAdd(&acc[e0 & (PSZ - 1)][lane], v0);
            atomicAdd(&acc[e1 & (PSZ - 1)][lane], v1);
            atomicAdd(&acc[e2 & (PSZ - 1)][lane], v2);
            atomicAdd(&acc[e3 & (PSZ - 1)][lane], v3);
        }
        for (; i < hi; i++) {
            unsigned e = ebuf[i];
            atomicAdd(&acc[e & (PSZ - 1)][lane], hs[(size_t)(e >> PBITS) * N_D + lane]);
        }
    }
    __syncthreads();

    for (int r = w; r < PSZ; r += 4) {
        int node = p * PSZ + r;
        if (node >= N) break;
        float d = dis[node];
        float selfv = hs[(size_t)node * N_D + lane];
        out[(size_t)node * N_D + lane] =
            d * (acc[r][lane] + selfv) / (float)(indeg[r] + 1);
    }
}

extern "C" void kernel_launch(void* const* d_in, const int* in_sizes, int n_in,
                              void* d_out, int out_size, void* d_ws, size_t ws_size,
                              hipStream_t stream) {
    const float* x = (const float*)d_in[0];
    const float* W = (const float*)d_in[1];
    const float* b = (const float*)d_in[2];
    const int* edge_index = (const int*)d_in[3];

    const int N = in_sizes[0] / N_D;  // 100000
    const int E = in_sizes[3] / 2;    // 1600000
    const int* src = edge_index;      // edge_index[0, :]
    const int* dst = edge_index + E;  // edge_index[1, :]
    float* out = (float*)d_out;

    const int P = (N + PSZ - 1) / PSZ;  // 782

    // workspace layout (~34.5 MB)
    char* ws = (char*)d_ws;
    size_t off = 0;
    float* hs = (float*)(ws + off);           off += (size_t)N * N_D * sizeof(float);
    float* dis = (float*)(ws + off);          off += (size_t)N * sizeof(float);
    unsigned* epart = (unsigned*)(ws + off);  off += (size_t)E * sizeof(unsigned);
    unsigned char* spart = (unsigned char*)(ws + off); off += ((size_t)E + 3) & ~3ull;
    int* cntD = (int*)(ws + off);             off += (size_t)(P + 1) * sizeof(int);
    int* cntS = (int*)(ws + off);             off += (size_t)(P + 1) * sizeof(int);
    int* startD = (int*)(ws + off);           off += (size_t)(P + 1) * sizeof(int);
    int* startS = (int*)(ws + off);           off += (size_t)(P + 1) * sizeof(int);
    int* cursorD = (int*)(ws + off);          off += (size_t)(P + 1) * sizeof(int);
    int* cursorS = (int*)(ws + off);          off += (size_t)(P + 1) * sizeof(int);
    (void)ws_size;

    const int HB = 256;  // blocks for hist/scatter passes
    size_t lds_hist = 2u * P * sizeof(int);
    size_t lds_scat = 4u * P * sizeof(int);

    zero_kernel<<<(P + 255) / 256, 256, 0, stream>>>(cntD, cntS, P);
    coarse_hist_kernel<<<HB, 256, lds_hist, stream>>>(src, dst, cntD, cntS, E, P);
    scan_kernel<<<1, 1024, 0, stream>>>(cntD, cntS, startD, cursorD, startS, cursorS, P);
    coarse_scatter_kernel<<<HB, 256, lds_scat, stream>>>(src, dst, cursorD, cursorS,
                                                         epart, spart, E, P);
    outdeg_dis_kernel<<<P, 256, 0, stream>>>(spart, startS, dis, N);

    int gLin = (N + ROWS_PB - 1) / ROWS_PB;
    linear_kernel<<<gLin, 256, 0, stream>>>(x, W, b, dis, hs, N);

    partition_gather_kernel<<<P, 256, 0, stream>>>(epart, startD, hs, dis, out, N);
}

// Round 4
// 260.274 us; speedup vs baseline: 3.3486x; 3.3486x over previous
//
#include <hip/hip_runtime.h>

#define N_D 64
#define PBITS 7
#define PSZ 128  // nodes per partition; P = ceil(N/128) = 782 for N=100000

// ---------------- zero partition counters ----------------
__global__ __launch_bounds__(256) void zero_kernel(int* __restrict__ cntD,
                                                   int* __restrict__ cntS, int P) {
    int i = blockIdx.x * 256 + threadIdx.x;
    if (i < P) { cntD[i] = 0; cntS[i] = 0; }
}

// ---------------- coarse histogram by partition (dst and src) ----------------
__global__ __launch_bounds__(256) void coarse_hist_kernel(const int* __restrict__ src,
                                                          const int* __restrict__ dst,
                                                          int* __restrict__ cntD,
                                                          int* __restrict__ cntS,
                                                          int E, int P) {
    extern __shared__ int sh[];  // 2*P ints
    int* hD = sh;
    int* hS = sh + P;
    int t = threadIdx.x;
    for (int i = t; i < 2 * P; i += 256) sh[i] = 0;
    __syncthreads();
    int per = (E + gridDim.x - 1) / gridDim.x;
    int beg = blockIdx.x * per, end = min(E, beg + per);
    for (int e = beg + t; e < end; e += 256) {
        atomicAdd(&hD[dst[e] >> PBITS], 1);
        atomicAdd(&hS[src[e] >> PBITS], 1);
    }
    __syncthreads();
    for (int p = t; p < P; p += 256) {
        if (hD[p]) atomicAdd(&cntD[p], hD[p]);
        if (hS[p]) atomicAdd(&cntS[p], hS[p]);
    }
}

// ---------------- parallel scan over P partials (both arrays), 1 block ----------------
__global__ __launch_bounds__(1024) void scan_kernel(const int* __restrict__ cntD,
                                                    const int* __restrict__ cntS,
                                                    int* __restrict__ startD,
                                                    int* __restrict__ cursorD,
                                                    int* __restrict__ startS,
                                                    int* __restrict__ cursorS, int P) {
    __shared__ int s[1024];
    int t = threadIdx.x;
    // ---- scan D ----
    int v = (t < P) ? cntD[t] : 0;
    s[t] = v;
    __syncthreads();
    for (int off = 1; off < 1024; off <<= 1) {
        int x = (t >= off) ? s[t - off] : 0;
        __syncthreads();
        s[t] += x;
        __syncthreads();
    }
    if (t < P) { int ex = s[t] - v; startD[t] = ex; cursorD[t] = ex; }
    if (t == 1023) startD[P] = s[1023];
    __syncthreads();
    // ---- scan S ----
    v = (t < P) ? cntS[t] : 0;
    s[t] = v;
    __syncthreads();
    for (int off = 1; off < 1024; off <<= 1) {
        int x = (t >= off) ? s[t - off] : 0;
        __syncthreads();
        s[t] += x;
        __syncthreads();
    }
    if (t < P) { int ex = s[t] - v; startS[t] = ex; cursorS[t] = ex; }
    if (t == 1023) startS[P] = s[1023];
}

// ---------------- scatter edges into partition ranges ----------------
// epart entry: (src << 7) | (dst & 127)   (src < 2^17 on this problem)
// spart entry: (uchar)(src & 127)
__global__ __launch_bounds__(256) void coarse_scatter_kernel(const int* __restrict__ src,
                                                             const int* __restrict__ dst,
                                                             int* __restrict__ cursorD,
                                                             int* __restrict__ cursorS,
                                                             unsigned* __restrict__ epart,
                                                             unsigned char* __restrict__ spart,
                                                             int E, int P) {
    extern __shared__ int sh[];  // 4*P ints: hD, hS, bD, bS
    int* hD = sh;
    int* hS = sh + P;
    int* bD = sh + 2 * P;
    int* bS = sh + 3 * P;
    int t = threadIdx.x;
    for (int i = t; i < 2 * P; i += 256) sh[i] = 0;
    __syncthreads();
    int per = (E + gridDim.x - 1) / gridDim.x;
    int beg = blockIdx.x * per, end = min(E, beg + per);
    // pass 1: local histograms
    for (int e = beg + t; e < end; e += 256) {
        atomicAdd(&hD[dst[e] >> PBITS], 1);
        atomicAdd(&hS[src[e] >> PBITS], 1);
    }
    __syncthreads();
    // reserve contiguous chunks per (block, partition); reset local cursors
    for (int p = t; p < P; p += 256) {
        int hd = hD[p];
        if (hd) bD[p] = atomicAdd(&cursorD[p], hd);
        hD[p] = 0;
        int hs_ = hS[p];
        if (hs_) bS[p] = atomicAdd(&cursorS[p], hs_);
        hS[p] = 0;
    }
    __syncthreads();
    // pass 2: place edges
    for (int e = beg + t; e < end; e += 256) {
        int d = dst[e], s0 = src[e];
        int pd = d >> PBITS, ps = s0 >> PBITS;
        int od = atomicAdd(&hD[pd], 1);
        epart[bD[pd] + od] = ((unsigned)s0 << PBITS) | (unsigned)(d & (PSZ - 1));
        int os = atomicAdd(&hS[ps], 1);
        spart[bS[ps] + os] = (unsigned char)(s0 & (PSZ - 1));
    }
}

// ---------------- per-partition out-degree histogram -> dis = rsqrt(deg+1) ----------------
__global__ __launch_bounds__(256) void outdeg_dis_kernel(const unsigned char* __restrict__ spart,
                                                         const int* __restrict__ startS,
                                                         float* __restrict__ dis, int N) {
    __shared__ int hist[PSZ];
    int p = blockIdx.x, t = threadIdx.x;
    if (t < PSZ) hist[t] = 0;
    __syncthreads();
    int beg = startS[p], end = startS[p + 1];
    for (int i = beg + t; i < end; i += 256) atomicAdd(&hist[spart[i]], 1);
    __syncthreads();
    if (t < PSZ) {
        int node = p * PSZ + t;
        if (node < N) dis[node] = rsqrtf((float)(hist[t] + 1));
    }
}

// ---------------- refine: per-partition counting sort by dst-local -> full CSR ----------------
// csr[row_start[node] .. ) = src indices of in-edges of node
__global__ __launch_bounds__(256) void refine_kernel(const unsigned* __restrict__ epart,
                                                     const int* __restrict__ startD,
                                                     int* __restrict__ csr,
                                                     int* __restrict__ row_start, int N) {
    __shared__ int hist[PSZ];
    __shared__ int ss[PSZ];
    __shared__ int cursor[PSZ];
    int p = blockIdx.x, t = threadIdx.x;
    if (t < PSZ) hist[t] = 0;
    __syncthreads();
    int beg = startD[p], end = startD[p + 1];
    for (int i = beg + t; i < end; i += 256)
        atomicAdd(&hist[epart[i] & (PSZ - 1)], 1);
    __syncthreads();
    int v = 0;
    if (t < PSZ) { v = hist[t]; ss[t] = v; }
    __syncthreads();
    // Hillis-Steele inclusive scan over 128 bins
    for (int off = 1; off < PSZ; off <<= 1) {
        int x = 0;
        if (t < PSZ && t >= off) x = ss[t - off];
        __syncthreads();
        if (t < PSZ) ss[t] += x;
        __syncthreads();
    }
    if (t < PSZ) {
        int excl = ss[t] - v;
        int node = p * PSZ + t;
        if (node < N) row_start[node] = beg + excl;
        cursor[t] = beg + excl;
    }
    if (t == 0 && p == gridDim.x - 1) row_start[N] = end;
    __syncthreads();
    for (int i = beg + t; i < end; i += 256) {
        unsigned e = epart[i];
        int pos = atomicAdd(&cursor[e & (PSZ - 1)], 1);
        csr[pos] = (int)(e >> PBITS);
    }
}

// ---------------- hs = dis * (x @ W^T + b) ----------------
#define ROWS_PB 32
__global__ __launch_bounds__(256) void linear_kernel(const float* __restrict__ x,
                                                     const float* __restrict__ W,
                                                     const float* __restrict__ b,
                                                     const float* __restrict__ dis,
                                                     float* __restrict__ hs, int N) {
    __shared__ float Ws[N_D][N_D + 1];
    __shared__ float bs[N_D];
    __shared__ float xs[ROWS_PB][N_D];

    int tid = threadIdx.x;
    for (int i = tid; i < N_D * N_D; i += 256)
        Ws[i >> 6][i & 63] = W[i];
    if (tid < N_D) bs[tid] = b[tid];

    int row0 = blockIdx.x * ROWS_PB;
    const float4* x4 = (const float4*)(x + (size_t)row0 * N_D);
    float4* xs4 = (float4*)&xs[0][0];
    const int n4 = ROWS_PB * N_D / 4;  // 512 float4s
    if (row0 + ROWS_PB <= N) {
        for (int i = tid; i < n4; i += 256) xs4[i] = x4[i];
    } else {
        for (int i = tid; i < n4; i += 256) {
            int row = row0 + (i >> 4);
            float4 v = make_float4(0.f, 0.f, 0.f, 0.f);
            if (row < N) v = x4[i];
            xs4[i] = v;
        }
    }
    __syncthreads();

    int o = tid & 63;
    int r0 = tid >> 6;
    float acc[ROWS_PB / 4];
#pragma unroll
    for (int j = 0; j < ROWS_PB / 4; j++) acc[j] = 0.f;

#pragma unroll 8
    for (int k = 0; k < N_D; k++) {
        float w = Ws[o][k];
#pragma unroll
        for (int j = 0; j < ROWS_PB / 4; j++)
            acc[j] += xs[r0 + 4 * j][k] * w;
    }

#pragma unroll
    for (int j = 0; j < ROWS_PB / 4; j++) {
        int row = row0 + r0 + 4 * j;
        if (row < N) hs[(size_t)row * N_D + o] = (acc[j] + bs[o]) * dis[row];
    }
}

// ---------------- gather: one wave per node, register accumulation ----------------
// out[i] = dis[i] * (hs[i] + sum_{e: dst==i} hs[src[e]]) / (indeg[i]+1)
__global__ __launch_bounds__(256, 8) void gather_kernel(const float* __restrict__ hs,
                                                        const float* __restrict__ dis,
                                                        const int* __restrict__ row_start,
                                                        const int* __restrict__ csr,
                                                        float* __restrict__ out, int N) {
    int wid = (blockIdx.x << 2) + (threadIdx.x >> 6);
    if (wid >= N) return;
    int lane = threadIdx.x & 63;

    int beg = row_start[wid];
    int num = row_start[wid + 1] - beg;
    const int* bp = csr + beg;

    float acc = hs[(size_t)wid * N_D + lane];  // self loop
    int j = 0;
    for (; j + 8 <= num; j += 8) {
        int s0 = bp[j + 0], s1 = bp[j + 1], s2 = bp[j + 2], s3 = bp[j + 3];
        int s4 = bp[j + 4], s5 = bp[j + 5], s6 = bp[j + 6], s7 = bp[j + 7];
        float v0 = hs[(size_t)s0 * N_D + lane];
        float v1 = hs[(size_t)s1 * N_D + lane];
        float v2 = hs[(size_t)s2 * N_D + lane];
        float v3 = hs[(size_t)s3 * N_D + lane];
        float v4 = hs[(size_t)s4 * N_D + lane];
        float v5 = hs[(size_t)s5 * N_D + lane];
        float v6 = hs[(size_t)s6 * N_D + lane];
        float v7 = hs[(size_t)s7 * N_D + lane];
        acc += v0; acc += v1; acc += v2; acc += v3;
        acc += v4; acc += v5; acc += v6; acc += v7;
    }
    for (; j < num; j++) acc += hs[(size_t)bp[j] * N_D + lane];

    out[(size_t)wid * N_D + lane] = dis[wid] * acc / (float)(num + 1);
}

extern "C" void kernel_launch(void* const* d_in, const int* in_sizes, int n_in,
                              void* d_out, int out_size, void* d_ws, size_t ws_size,
                              hipStream_t stream) {
    const float* x = (const float*)d_in[0];
    const float* W = (const float*)d_in[1];
    const float* b = (const float*)d_in[2];
    const int* edge_index = (const int*)d_in[3];

    const int N = in_sizes[0] / N_D;  // 100000
    const int E = in_sizes[3] / 2;    // 1600000
    const int* src = edge_index;      // edge_index[0, :]
    const int* dst = edge_index + E;  // edge_index[1, :]
    float* out = (float*)d_out;

    const int P = (N + PSZ - 1) / PSZ;  // 782

    // workspace layout (~41 MB)
    char* ws = (char*)d_ws;
    size_t off = 0;
    float* hs = (float*)(ws + off);           off += (size_t)N * N_D * sizeof(float);
    float* dis = (float*)(ws + off);          off += (size_t)N * sizeof(float);
    unsigned* epart = (unsigned*)(ws + off);  off += (size_t)E * sizeof(unsigned);
    int* csr = (int*)(ws + off);              off += (size_t)E * sizeof(int);
    int* row_start = (int*)(ws + off);        off += (size_t)(N + 1) * sizeof(int);
    unsigned char* spart = (unsigned char*)(ws + off); off += ((size_t)E + 3) & ~3ull;
    int* cntD = (int*)(ws + off);             off += (size_t)(P + 1) * sizeof(int);
    int* cntS = (int*)(ws + off);             off += (size_t)(P + 1) * sizeof(int);
    int* startD = (int*)(ws + off);           off += (size_t)(P + 1) * sizeof(int);
    int* startS = (int*)(ws + off);           off += (size_t)(P + 1) * sizeof(int);
    int* cursorD = (int*)(ws + off);          off += (size_t)(P + 1) * sizeof(int);
    int* cursorS = (int*)(ws + off);          off += (size_t)(P + 1) * sizeof(int);
    (void)ws_size;

    const int HB = 256;  // blocks for hist/scatter passes
    size_t lds_hist = 2u * P * sizeof(int);
    size_t lds_scat = 4u * P * sizeof(int);

    zero_kernel<<<(P + 255) / 256, 256, 0, stream>>>(cntD, cntS, P);
    coarse_hist_kernel<<<HB, 256, lds_hist, stream>>>(src, dst, cntD, cntS, E, P);
    scan_kernel<<<1, 1024, 0, stream>>>(cntD, cntS, startD, cursorD, startS, cursorS, P);
    coarse_scatter_kernel<<<HB, 256, lds_scat, stream>>>(src, dst, cursorD, cursorS,
                                                         epart, spart, E, P);
    outdeg_dis_kernel<<<P, 256, 0, stream>>>(spart, startS, dis, N);
    refine_kernel<<<P, 256, 0, stream>>>(epart, startD, csr, row_start, N);

    int gLin = (N + ROWS_PB - 1) / ROWS_PB;
    linear_kernel<<<gLin, 256, 0, stream>>>(x, W, b, dis, hs, N);

    int gGat = (N + 3) / 4;  // 4 waves (nodes) per block
    gather_kernel<<<gGat, 256, 0, stream>>>(hs, dis, row_start, csr, out, N);
}

// Round 5
// 256.775 us; speedup vs baseline: 3.3942x; 1.0136x over previous
//
#include <hip/hip_runtime.h>
#include <hip/hip_fp16.h>

#define N_D 64
#define PBITS 7
#define PSZ 128  // nodes per partition; P = ceil(N/128) = 782 for N=100000

// ---------------- coarse histogram by partition (dst and src) ----------------
__global__ __launch_bounds__(256) void coarse_hist_kernel(const int* __restrict__ src,
                                                          const int* __restrict__ dst,
                                                          int* __restrict__ cntD,
                                                          int* __restrict__ cntS,
                                                          int E, int P) {
    extern __shared__ int sh[];  // 2*P ints
    int* hD = sh;
    int* hS = sh + P;
    int t = threadIdx.x;
    for (int i = t; i < 2 * P; i += 256) sh[i] = 0;
    __syncthreads();
    int per = (E + gridDim.x - 1) / gridDim.x;
    int beg = blockIdx.x * per, end = min(E, beg + per);
    for (int e = beg + t; e < end; e += 256) {
        atomicAdd(&hD[dst[e] >> PBITS], 1);
        atomicAdd(&hS[src[e] >> PBITS], 1);
    }
    __syncthreads();
    for (int p = t; p < P; p += 256) {
        if (hD[p]) atomicAdd(&cntD[p], hD[p]);
        if (hS[p]) atomicAdd(&cntS[p], hS[p]);
    }
}

// ---------------- parallel scan over P partials (both arrays), 1 block ----------------
__global__ __launch_bounds__(1024) void scan_kernel(const int* __restrict__ cntD,
                                                    const int* __restrict__ cntS,
                                                    int* __restrict__ startD,
                                                    int* __restrict__ cursorD,
                                                    int* __restrict__ startS,
                                                    int* __restrict__ cursorS, int P) {
    __shared__ int s[1024];
    int t = threadIdx.x;
    // ---- scan D ----
    int v = (t < P) ? cntD[t] : 0;
    s[t] = v;
    __syncthreads();
    for (int off = 1; off < 1024; off <<= 1) {
        int x = (t >= off) ? s[t - off] : 0;
        __syncthreads();
        s[t] += x;
        __syncthreads();
    }
    if (t < P) { int ex = s[t] - v; startD[t] = ex; cursorD[t] = ex; }
    if (t == 1023) startD[P] = s[1023];
    __syncthreads();
    // ---- scan S ----
    v = (t < P) ? cntS[t] : 0;
    s[t] = v;
    __syncthreads();
    for (int off = 1; off < 1024; off <<= 1) {
        int x = (t >= off) ? s[t - off] : 0;
        __syncthreads();
        s[t] += x;
        __syncthreads();
    }
    if (t < P) { int ex = s[t] - v; startS[t] = ex; cursorS[t] = ex; }
    if (t == 1023) startS[P] = s[1023];
}

// ---------------- scatter edges into partition ranges ----------------
// epart entry: (src << 7) | (dst & 127)   (src < 2^17 on this problem)
// spart entry: (uchar)(src & 127)
__global__ __launch_bounds__(256) void coarse_scatter_kernel(const int* __restrict__ src,
                                                             const int* __restrict__ dst,
                                                             int* __restrict__ cursorD,
                                                             int* __restrict__ cursorS,
                                                             unsigned* __restrict__ epart,
                                                             unsigned char* __restrict__ spart,
                                                             int E, int P) {
    extern __shared__ int sh[];  // 4*P ints: hD, hS, bD, bS
    int* hD = sh;
    int* hS = sh + P;
    int* bD = sh + 2 * P;
    int* bS = sh + 3 * P;
    int t = threadIdx.x;
    for (int i = t; i < 2 * P; i += 256) sh[i] = 0;
    __syncthreads();
    int per = (E + gridDim.x - 1) / gridDim.x;
    int beg = blockIdx.x * per, end = min(E, beg + per);
    // pass 1: local histograms
    for (int e = beg + t; e < end; e += 256) {
        atomicAdd(&hD[dst[e] >> PBITS], 1);
        atomicAdd(&hS[src[e] >> PBITS], 1);
    }
    __syncthreads();
    // reserve contiguous chunks per (block, partition); reset local cursors
    for (int p = t; p < P; p += 256) {
        int hd = hD[p];
        if (hd) bD[p] = atomicAdd(&cursorD[p], hd);
        hD[p] = 0;
        int hs_ = hS[p];
        if (hs_) bS[p] = atomicAdd(&cursorS[p], hs_);
        hS[p] = 0;
    }
    __syncthreads();
    // pass 2: place edges
    for (int e = beg + t; e < end; e += 256) {
        int d = dst[e], s0 = src[e];
        int pd = d >> PBITS, ps = s0 >> PBITS;
        int od = atomicAdd(&hD[pd], 1);
        epart[bD[pd] + od] = ((unsigned)s0 << PBITS) | (unsigned)(d & (PSZ - 1));
        int os = atomicAdd(&hS[ps], 1);
        spart[bS[ps] + os] = (unsigned char)(s0 & (PSZ - 1));
    }
}

// ---------------- fused refine: outdeg->dis AND counting-sort epart -> CSR ----------------
__global__ __launch_bounds__(256) void refine_kernel(const unsigned* __restrict__ epart,
                                                     const unsigned char* __restrict__ spart,
                                                     const int* __restrict__ startD,
                                                     const int* __restrict__ startS,
                                                     int* __restrict__ csr,
                                                     int* __restrict__ row_start,
                                                     float* __restrict__ dis, int N) {
    __shared__ int hist[PSZ];
    __shared__ int ss[PSZ];
    __shared__ int cursor[PSZ];
    __shared__ int ohist[PSZ];
    int p = blockIdx.x, t = threadIdx.x;
    if (t < PSZ) { hist[t] = 0; ohist[t] = 0; }
    __syncthreads();

    // --- out-degree histogram (src side) -> dis ---
    int sbeg = startS[p], send = startS[p + 1];
    for (int i = sbeg + t; i < send; i += 256) atomicAdd(&ohist[spart[i]], 1);

    // --- in-edge histogram (dst side) ---
    int beg = startD[p], end = startD[p + 1];
    for (int i = beg + t; i < end; i += 256)
        atomicAdd(&hist[epart[i] & (PSZ - 1)], 1);
    __syncthreads();

    if (t < PSZ) {
        int node = p * PSZ + t;
        if (node < N) dis[node] = rsqrtf((float)(ohist[t] + 1));
    }

    int v = 0;
    if (t < PSZ) { v = hist[t]; ss[t] = v; }
    __syncthreads();
    // Hillis-Steele inclusive scan over 128 bins
    for (int off = 1; off < PSZ; off <<= 1) {
        int x = 0;
        if (t < PSZ && t >= off) x = ss[t - off];
        __syncthreads();
        if (t < PSZ) ss[t] += x;
        __syncthreads();
    }
    if (t < PSZ) {
        int excl = ss[t] - v;
        int node = p * PSZ + t;
        if (node < N) row_start[node] = beg + excl;
        cursor[t] = beg + excl;
    }
    if (t == 0 && p == gridDim.x - 1) row_start[N] = end;
    __syncthreads();
    for (int i = beg + t; i < end; i += 256) {
        unsigned e = epart[i];
        int pos = atomicAdd(&cursor[e & (PSZ - 1)], 1);
        csr[pos] = (int)(e >> PBITS);
    }
}

// ---------------- hs(fp16) = dis * (x @ W^T + b) ----------------
#define ROWS_PB 32
__global__ __launch_bounds__(256) void linear_kernel(const float* __restrict__ x,
                                                     const float* __restrict__ W,
                                                     const float* __restrict__ b,
                                                     const float* __restrict__ dis,
                                                     __half* __restrict__ hs, int N) {
    __shared__ float Ws[N_D][N_D + 1];
    __shared__ float bs[N_D];
    __shared__ float xs[ROWS_PB][N_D];

    int tid = threadIdx.x;
    for (int i = tid; i < N_D * N_D; i += 256)
        Ws[i >> 6][i & 63] = W[i];
    if (tid < N_D) bs[tid] = b[tid];

    int row0 = blockIdx.x * ROWS_PB;
    const float4* x4 = (const float4*)(x + (size_t)row0 * N_D);
    float4* xs4 = (float4*)&xs[0][0];
    const int n4 = ROWS_PB * N_D / 4;  // 512 float4s
    if (row0 + ROWS_PB <= N) {
        for (int i = tid; i < n4; i += 256) xs4[i] = x4[i];
    } else {
        for (int i = tid; i < n4; i += 256) {
            int row = row0 + (i >> 4);
            float4 v = make_float4(0.f, 0.f, 0.f, 0.f);
            if (row < N) v = x4[i];
            xs4[i] = v;
        }
    }
    __syncthreads();

    int o = tid & 63;
    int r0 = tid >> 6;
    float acc[ROWS_PB / 4];
#pragma unroll
    for (int j = 0; j < ROWS_PB / 4; j++) acc[j] = 0.f;

#pragma unroll 8
    for (int k = 0; k < N_D; k++) {
        float w = Ws[o][k];
#pragma unroll
        for (int j = 0; j < ROWS_PB / 4; j++)
            acc[j] += xs[r0 + 4 * j][k] * w;
    }

#pragma unroll
    for (int j = 0; j < ROWS_PB / 4; j++) {
        int row = row0 + r0 + 4 * j;
        if (row < N)
            hs[(size_t)row * N_D + o] = __float2half_rn((acc[j] + bs[o]) * dis[row]);
    }
}

// ---------------- gather: one wave per node, register accumulation ----------------
// out[i] = dis[i] * (hs[i] + sum_{e: dst==i} hs[src[e]]) / (indeg[i]+1)
__global__ __launch_bounds__(256, 8) void gather_kernel(const __half* __restrict__ hs,
                                                        const float* __restrict__ dis,
                                                        const int* __restrict__ row_start,
                                                        const int* __restrict__ csr,
                                                        float* __restrict__ out, int N) {
    int wid = (blockIdx.x << 2) + (threadIdx.x >> 6);
    if (wid >= N) return;
    int lane = threadIdx.x & 63;

    int beg = row_start[wid];
    int num = row_start[wid + 1] - beg;
    const int* bp = csr + beg;

    float acc = __half2float(hs[(size_t)wid * N_D + lane]);  // self loop
    int j = 0;
    for (; j + 8 <= num; j += 8) {
        int s0 = bp[j + 0], s1 = bp[j + 1], s2 = bp[j + 2], s3 = bp[j + 3];
        int s4 = bp[j + 4], s5 = bp[j + 5], s6 = bp[j + 6], s7 = bp[j + 7];
        float v0 = __half2float(hs[(size_t)s0 * N_D + lane]);
        float v1 = __half2float(hs[(size_t)s1 * N_D + lane]);
        float v2 = __half2float(hs[(size_t)s2 * N_D + lane]);
        float v3 = __half2float(hs[(size_t)s3 * N_D + lane]);
        float v4 = __half2float(hs[(size_t)s4 * N_D + lane]);
        float v5 = __half2float(hs[(size_t)s5 * N_D + lane]);
        float v6 = __half2float(hs[(size_t)s6 * N_D + lane]);
        float v7 = __half2float(hs[(size_t)s7 * N_D + lane]);
        acc += v0; acc += v1; acc += v2; acc += v3;
        acc += v4; acc += v5; acc += v6; acc += v7;
    }
    for (; j < num; j++) acc += __half2float(hs[(size_t)bp[j] * N_D + lane]);

    out[(size_t)wid * N_D + lane] = dis[wid] * acc / (float)(num + 1);
}

extern "C" void kernel_launch(void* const* d_in, const int* in_sizes, int n_in,
                              void* d_out, int out_size, void* d_ws, size_t ws_size,
                              hipStream_t stream) {
    const float* x = (const float*)d_in[0];
    const float* W = (const float*)d_in[1];
    const float* b = (const float*)d_in[2];
    const int* edge_index = (const int*)d_in[3];

    const int N = in_sizes[0] / N_D;  // 100000
    const int E = in_sizes[3] / 2;    // 1600000
    const int* src = edge_index;      // edge_index[0, :]
    const int* dst = edge_index + E;  // edge_index[1, :]
    float* out = (float*)d_out;

    const int P = (N + PSZ - 1) / PSZ;  // 782

    // workspace layout (~29 MB)
    char* ws = (char*)d_ws;
    size_t off = 0;
    __half* hs = (__half*)(ws + off);         off += ((size_t)N * N_D * sizeof(__half) + 15) & ~15ull;
    float* dis = (float*)(ws + off);          off += (size_t)N * sizeof(float);
    unsigned* epart = (unsigned*)(ws + off);  off += (size_t)E * sizeof(unsigned);
    int* csr = (int*)(ws + off);              off += (size_t)E * sizeof(int);
    int* row_start = (int*)(ws + off);        off += (size_t)(N + 1) * sizeof(int);
    unsigned char* spart = (unsigned char*)(ws + off); off += ((size_t)E + 3) & ~3ull;
    int* cntD = (int*)(ws + off);             off += (size_t)(P + 1) * sizeof(int);
    int* cntS = (int*)(ws + off);             off += (size_t)(P + 1) * sizeof(int);
    int* startD = (int*)(ws + off);           off += (size_t)(P + 1) * sizeof(int);
    int* startS = (int*)(ws + off);           off += (size_t)(P + 1) * sizeof(int);
    int* cursorD = (int*)(ws + off);          off += (size_t)(P + 1) * sizeof(int);
    int* cursorS = (int*)(ws + off);          off += (size_t)(P + 1) * sizeof(int);
    (void)ws_size;

    const int HB = 256;  // blocks for hist/scatter passes
    size_t lds_hist = 2u * P * sizeof(int);
    size_t lds_scat = 4u * P * sizeof(int);

    // zero the two count arrays (contiguous in ws) in one memset
    hipMemsetAsync(cntD, 0, 2u * (P + 1) * sizeof(int), stream);

    coarse_hist_kernel<<<HB, 256, lds_hist, stream>>>(src, dst, cntD, cntS, E, P);
    scan_kernel<<<1, 1024, 0, stream>>>(cntD, cntS, startD, cursorD, startS, cursorS, P);
    coarse_scatter_kernel<<<HB, 256, lds_scat, stream>>>(src, dst, cursorD, cursorS,
                                                         epart, spart, E, P);
    refine_kernel<<<P, 256, 0, stream>>>(epart, spart, startD, startS,
                                         csr, row_start, dis, N);

    int gLin = (N + ROWS_PB - 1) / ROWS_PB;
    linear_kernel<<<gLin, 256, 0, stream>>>(x, W, b, dis, hs, N);

    int gGat = (N + 3) / 4;  // 4 waves (nodes) per block
    gather_kernel<<<gGat, 256, 0, stream>>>(hs, dis, row_start, csr, out, N);
}

// Round 6
// 236.043 us; speedup vs baseline: 3.6923x; 1.0878x over previous
//
#include <hip/hip_runtime.h>
#include <hip/hip_fp16.h>

#define N_D 64
#define PBITS 7
#define PSZ 128  // nodes per partition; P = ceil(N/128) = 782 for N=100000

// ---------------- coarse histogram by partition (dst and src), int4 edge reads ----------------
__global__ __launch_bounds__(256) void coarse_hist_kernel(const int* __restrict__ src,
                                                          const int* __restrict__ dst,
                                                          int* __restrict__ cntD,
                                                          int* __restrict__ cntS,
                                                          int E, int P) {
    extern __shared__ int sh[];  // 2*P ints
    int* hD = sh;
    int* hS = sh + P;
    int t = threadIdx.x;
    for (int i = t; i < 2 * P; i += 256) sh[i] = 0;
    __syncthreads();
    const int4* src4 = (const int4*)src;
    const int4* dst4 = (const int4*)dst;
    int E4 = E >> 2;
    int per = (E4 + gridDim.x - 1) / gridDim.x;
    int beg = blockIdx.x * per, end = min(E4, beg + per);
    for (int e = beg + t; e < end; e += 256) {
        int4 d = dst4[e];
        int4 s = src4[e];
        atomicAdd(&hD[d.x >> PBITS], 1);
        atomicAdd(&hD[d.y >> PBITS], 1);
        atomicAdd(&hD[d.z >> PBITS], 1);
        atomicAdd(&hD[d.w >> PBITS], 1);
        atomicAdd(&hS[s.x >> PBITS], 1);
        atomicAdd(&hS[s.y >> PBITS], 1);
        atomicAdd(&hS[s.z >> PBITS], 1);
        atomicAdd(&hS[s.w >> PBITS], 1);
    }
    if (blockIdx.x == 0) {  // scalar tail (E not multiple of 4)
        for (int e = (E4 << 2) + t; e < E; e += 256) {
            atomicAdd(&hD[dst[e] >> PBITS], 1);
            atomicAdd(&hS[src[e] >> PBITS], 1);
        }
    }
    __syncthreads();
    for (int p = t; p < P; p += 256) {
        if (hD[p]) atomicAdd(&cntD[p], hD[p]);
        if (hS[p]) atomicAdd(&cntS[p], hS[p]);
    }
}

// ---------------- parallel scan over P partials (both arrays), 1 block ----------------
__global__ __launch_bounds__(1024) void scan_kernel(const int* __restrict__ cntD,
                                                    const int* __restrict__ cntS,
                                                    int* __restrict__ startD,
                                                    int* __restrict__ cursorD,
                                                    int* __restrict__ startS,
                                                    int* __restrict__ cursorS, int P) {
    __shared__ int s[1024];
    int t = threadIdx.x;
    // ---- scan D ----
    int v = (t < P) ? cntD[t] : 0;
    s[t] = v;
    __syncthreads();
    for (int off = 1; off < 1024; off <<= 1) {
        int x = (t >= off) ? s[t - off] : 0;
        __syncthreads();
        s[t] += x;
        __syncthreads();
    }
    if (t < P) { int ex = s[t] - v; startD[t] = ex; cursorD[t] = ex; }
    if (t == 1023) startD[P] = s[1023];
    __syncthreads();
    // ---- scan S ----
    v = (t < P) ? cntS[t] : 0;
    s[t] = v;
    __syncthreads();
    for (int off = 1; off < 1024; off <<= 1) {
        int x = (t >= off) ? s[t - off] : 0;
        __syncthreads();
        s[t] += x;
        __syncthreads();
    }
    if (t < P) { int ex = s[t] - v; startS[t] = ex; cursorS[t] = ex; }
    if (t == 1023) startS[P] = s[1023];
}

// ---------------- scatter edges into partition ranges, int4 edge reads ----------------
// epart entry: (src << 7) | (dst & 127)   (src < 2^17 on this problem)
// spart entry: (uchar)(src & 127)
__global__ __launch_bounds__(256) void coarse_scatter_kernel(const int* __restrict__ src,
                                                             const int* __restrict__ dst,
                                                             int* __restrict__ cursorD,
                                                             int* __restrict__ cursorS,
                                                             unsigned* __restrict__ epart,
                                                             unsigned char* __restrict__ spart,
                                                             int E, int P) {
    extern __shared__ int sh[];  // 4*P ints: hD, hS, bD, bS
    int* hD = sh;
    int* hS = sh + P;
    int* bD = sh + 2 * P;
    int* bS = sh + 3 * P;
    int t = threadIdx.x;
    for (int i = t; i < 2 * P; i += 256) sh[i] = 0;
    __syncthreads();
    const int4* src4 = (const int4*)src;
    const int4* dst4 = (const int4*)dst;
    int E4 = E >> 2;
    int per = (E4 + gridDim.x - 1) / gridDim.x;
    int beg = blockIdx.x * per, end = min(E4, beg + per);
    bool tailblk = (blockIdx.x == 0);
    // pass 1: local histograms
    for (int e = beg + t; e < end; e += 256) {
        int4 d = dst4[e];
        int4 s = src4[e];
        atomicAdd(&hD[d.x >> PBITS], 1);
        atomicAdd(&hD[d.y >> PBITS], 1);
        atomicAdd(&hD[d.z >> PBITS], 1);
        atomicAdd(&hD[d.w >> PBITS], 1);
        atomicAdd(&hS[s.x >> PBITS], 1);
        atomicAdd(&hS[s.y >> PBITS], 1);
        atomicAdd(&hS[s.z >> PBITS], 1);
        atomicAdd(&hS[s.w >> PBITS], 1);
    }
    if (tailblk) {
        for (int e = (E4 << 2) + t; e < E; e += 256) {
            atomicAdd(&hD[dst[e] >> PBITS], 1);
            atomicAdd(&hS[src[e] >> PBITS], 1);
        }
    }
    __syncthreads();
    // reserve contiguous chunks per (block, partition); reset local cursors
    for (int p = t; p < P; p += 256) {
        int hd = hD[p];
        if (hd) bD[p] = atomicAdd(&cursorD[p], hd);
        hD[p] = 0;
        int hs_ = hS[p];
        if (hs_) bS[p] = atomicAdd(&cursorS[p], hs_);
        hS[p] = 0;
    }
    __syncthreads();
    // pass 2: place edges
    for (int e = beg + t; e < end; e += 256) {
        int4 dv = dst4[e];
        int4 sv = src4[e];
        int ds_[4] = {dv.x, dv.y, dv.z, dv.w};
        int ss_[4] = {sv.x, sv.y, sv.z, sv.w};
#pragma unroll
        for (int k = 0; k < 4; k++) {
            int d = ds_[k], s0 = ss_[k];
            int pd = d >> PBITS, ps = s0 >> PBITS;
            int od = atomicAdd(&hD[pd], 1);
            epart[bD[pd] + od] = ((unsigned)s0 << PBITS) | (unsigned)(d & (PSZ - 1));
            int os = atomicAdd(&hS[ps], 1);
            spart[bS[ps] + os] = (unsigned char)(s0 & (PSZ - 1));
        }
    }
    if (tailblk) {
        for (int e = (E4 << 2) + t; e < E; e += 256) {
            int d = dst[e], s0 = src[e];
            int pd = d >> PBITS, ps = s0 >> PBITS;
            int od = atomicAdd(&hD[pd], 1);
            epart[bD[pd] + od] = ((unsigned)s0 << PBITS) | (unsigned)(d & (PSZ - 1));
            int os = atomicAdd(&hS[ps], 1);
            spart[bS[ps] + os] = (unsigned char)(s0 & (PSZ - 1));
        }
    }
}

// ---------------- fused refine: outdeg->dis AND counting-sort epart -> CSR ----------------
// csr entries are BYTE offsets into hs: src*128 = epart_entry & ~127
__global__ __launch_bounds__(256) void refine_kernel(const unsigned* __restrict__ epart,
                                                     const unsigned char* __restrict__ spart,
                                                     const int* __restrict__ startD,
                                                     const int* __restrict__ startS,
                                                     int* __restrict__ csr,
                                                     int* __restrict__ row_start,
                                                     float* __restrict__ dis, int N) {
    __shared__ int hist[PSZ];
    __shared__ int ss[PSZ];
    __shared__ int cursor[PSZ];
    __shared__ int ohist[PSZ];
    int p = blockIdx.x, t = threadIdx.x;
    if (t < PSZ) { hist[t] = 0; ohist[t] = 0; }
    __syncthreads();

    // --- out-degree histogram (src side) -> dis ---
    int sbeg = startS[p], send = startS[p + 1];
    for (int i = sbeg + t; i < send; i += 256) atomicAdd(&ohist[spart[i]], 1);

    // --- in-edge histogram (dst side) ---
    int beg = startD[p], end = startD[p + 1];
    for (int i = beg + t; i < end; i += 256)
        atomicAdd(&hist[epart[i] & (PSZ - 1)], 1);
    __syncthreads();

    if (t < PSZ) {
        int node = p * PSZ + t;
        if (node < N) dis[node] = rsqrtf((float)(ohist[t] + 1));
    }

    int v = 0;
    if (t < PSZ) { v = hist[t]; ss[t] = v; }
    __syncthreads();
    // Hillis-Steele inclusive scan over 128 bins
    for (int off = 1; off < PSZ; off <<= 1) {
        int x = 0;
        if (t < PSZ && t >= off) x = ss[t - off];
        __syncthreads();
        if (t < PSZ) ss[t] += x;
        __syncthreads();
    }
    if (t < PSZ) {
        int excl = ss[t] - v;
        int node = p * PSZ + t;
        if (node < N) row_start[node] = beg + excl;
        cursor[t] = beg + excl;
    }
    if (t == 0 && p == gridDim.x - 1) row_start[N] = end;
    __syncthreads();
    for (int i = beg + t; i < end; i += 256) {
        unsigned e = epart[i];
        int pos = atomicAdd(&cursor[e & (PSZ - 1)], 1);
        csr[pos] = (int)(e & ~(unsigned)(PSZ - 1));  // byte offset: src*128
    }
}

// ---------------- hs(fp16) = dis * (x @ W^T + b) ----------------
#define ROWS_PB 32
__global__ __launch_bounds__(256) void linear_kernel(const float* __restrict__ x,
                                                     const float* __restrict__ W,
                                                     const float* __restrict__ b,
                                                     const float* __restrict__ dis,
                                                     __half* __restrict__ hs, int N) {
    __shared__ float Ws[N_D][N_D + 1];
    __shared__ float bs[N_D];
    __shared__ float xs[ROWS_PB][N_D];

    int tid = threadIdx.x;
    for (int i = tid; i < N_D * N_D; i += 256)
        Ws[i >> 6][i & 63] = W[i];
    if (tid < N_D) bs[tid] = b[tid];

    int row0 = blockIdx.x * ROWS_PB;
    const float4* x4 = (const float4*)(x + (size_t)row0 * N_D);
    float4* xs4 = (float4*)&xs[0][0];
    const int n4 = ROWS_PB * N_D / 4;  // 512 float4s
    if (row0 + ROWS_PB <= N) {
        for (int i = tid; i < n4; i += 256) xs4[i] = x4[i];
    } else {
        for (int i = tid; i < n4; i += 256) {
            int row = row0 + (i >> 4);
            float4 v = make_float4(0.f, 0.f, 0.f, 0.f);
            if (row < N) v = x4[i];
            xs4[i] = v;
        }
    }
    __syncthreads();

    int o = tid & 63;
    int r0 = tid >> 6;
    float acc[ROWS_PB / 4];
#pragma unroll
    for (int j = 0; j < ROWS_PB / 4; j++) acc[j] = 0.f;

#pragma unroll 8
    for (int k = 0; k < N_D; k++) {
        float w = Ws[o][k];
#pragma unroll
        for (int j = 0; j < ROWS_PB / 4; j++)
            acc[j] += xs[r0 + 4 * j][k] * w;
    }

#pragma unroll
    for (int j = 0; j < ROWS_PB / 4; j++) {
        int row = row0 + r0 + 4 * j;
        if (row < N)
            hs[(size_t)row * N_D + o] = __float2half_rn((acc[j] + bs[o]) * dis[row]);
    }
}

// ---------------- gather: one wave per TWO nodes, interleaved chains ----------------
__device__ __forceinline__ float hload(const char* hbase, int off, int lane2) {
    return __half2float(*(const __half*)(hbase + (size_t)(unsigned)off + lane2));
}

__global__ __launch_bounds__(256, 8) void gather_kernel(const __half* __restrict__ hs,
                                                        const float* __restrict__ dis,
                                                        const int* __restrict__ row_start,
                                                        const int* __restrict__ csr,
                                                        float* __restrict__ out, int N) {
    int wpair = (blockIdx.x << 2) + (threadIdx.x >> 6);
    int lane = threadIdx.x & 63;
    int lane2 = lane << 1;
    int nA = wpair << 1;
    if (nA >= N) return;
    int nB = nA + 1;
    bool hasB = nB < N;
    const char* hbase = (const char*)hs;

    int begA = row_start[nA];
    int endA = row_start[nA + 1];
    int begB = hasB ? row_start[nB] : 0;
    int endB = hasB ? row_start[nB + 1] : 0;
    int numA = endA - begA, numB = endB - begB;
    const int* pA = csr + begA;
    const int* pB = csr + begB;

    float accA = hload(hbase, nA << 7, lane2);  // self loop
    float accB = hasB ? hload(hbase, nB << 7, lane2) : 0.f;

    int iA = 0, iB = 0;
    // merged loop: 4 edges per node, 8 outstanding gathers across 2 chains
    while (iA + 4 <= numA && iB + 4 <= numB) {
        int a0 = pA[iA], a1 = pA[iA + 1], a2 = pA[iA + 2], a3 = pA[iA + 3];
        int b0 = pB[iB], b1 = pB[iB + 1], b2 = pB[iB + 2], b3 = pB[iB + 3];
        float va0 = hload(hbase, a0, lane2);
        float vb0 = hload(hbase, b0, lane2);
        float va1 = hload(hbase, a1, lane2);
        float vb1 = hload(hbase, b1, lane2);
        float va2 = hload(hbase, a2, lane2);
        float vb2 = hload(hbase, b2, lane2);
        float va3 = hload(hbase, a3, lane2);
        float vb3 = hload(hbase, b3, lane2);
        accA += va0; accB += vb0;
        accA += va1; accB += vb1;
        accA += va2; accB += vb2;
        accA += va3; accB += vb3;
        iA += 4; iB += 4;
    }
    // leftover A (8-unrolled)
    while (iA + 8 <= numA) {
        int a0 = pA[iA], a1 = pA[iA + 1], a2 = pA[iA + 2], a3 = pA[iA + 3];
        int a4 = pA[iA + 4], a5 = pA[iA + 5], a6 = pA[iA + 6], a7 = pA[iA + 7];
        float v0 = hload(hbase, a0, lane2);
        float v1 = hload(hbase, a1, lane2);
        float v2 = hload(hbase, a2, lane2);
        float v3 = hload(hbase, a3, lane2);
        float v4 = hload(hbase, a4, lane2);
        float v5 = hload(hbase, a5, lane2);
        float v6 = hload(hbase, a6, lane2);
        float v7 = hload(hbase, a7, lane2);
        accA += v0; accA += v1; accA += v2; accA += v3;
        accA += v4; accA += v5; accA += v6; accA += v7;
        iA += 8;
    }
    // leftover B (8-unrolled)
    while (iB + 8 <= numB) {
        int b0 = pB[iB], b1 = pB[iB + 1], b2 = pB[iB + 2], b3 = pB[iB + 3];
        int b4 = pB[iB + 4], b5 = pB[iB + 5], b6 = pB[iB + 6], b7 = pB[iB + 7];
        float v0 = hload(hbase, b0, lane2);
        float v1 = hload(hbase, b1, lane2);
        float v2 = hload(hbase, b2, lane2);
        float v3 = hload(hbase, b3, lane2);
        float v4 = hload(hbase, b4, lane2);
        float v5 = hload(hbase, b5, lane2);
        float v6 = hload(hbase, b6, lane2);
        float v7 = hload(hbase, b7, lane2);
        accB += v0; accB += v1; accB += v2; accB += v3;
        accB += v4; accB += v5; accB += v6; accB += v7;
        iB += 8;
    }
    for (; iA < numA; iA++) accA += hload(hbase, pA[iA], lane2);
    for (; iB < numB; iB++) accB += hload(hbase, pB[iB], lane2);

    out[((size_t)nA << 6) + lane] = dis[nA] * accA / (float)(numA + 1);
    if (hasB)
        out[((size_t)nB << 6) + lane] = dis[nB] * accB / (float)(numB + 1);
}

extern "C" void kernel_launch(void* const* d_in, const int* in_sizes, int n_in,
                              void* d_out, int out_size, void* d_ws, size_t ws_size,
                              hipStream_t stream) {
    const float* x = (const float*)d_in[0];
    const float* W = (const float*)d_in[1];
    const float* b = (const float*)d_in[2];
    const int* edge_index = (const int*)d_in[3];

    const int N = in_sizes[0] / N_D;  // 100000
    const int E = in_sizes[3] / 2;    // 1600000
    const int* src = edge_index;      // edge_index[0, :]
    const int* dst = edge_index + E;  // edge_index[1, :]
    float* out = (float*)d_out;

    const int P = (N + PSZ - 1) / PSZ;  // 782

    // workspace layout (~29 MB)
    char* ws = (char*)d_ws;
    size_t off = 0;
    __half* hs = (__half*)(ws + off);         off += ((size_t)N * N_D * sizeof(__half) + 15) & ~15ull;
    float* dis = (float*)(ws + off);          off += (size_t)N * sizeof(float);
    unsigned* epart = (unsigned*)(ws + off);  off += (size_t)E * sizeof(unsigned);
    int* csr = (int*)(ws + off);              off += (size_t)E * sizeof(int);
    int* row_start = (int*)(ws + off);        off += (size_t)(N + 1) * sizeof(int);
    unsigned char* spart = (unsigned char*)(ws + off); off += ((size_t)E + 3) & ~3ull;
    int* cntD = (int*)(ws + off);             off += (size_t)(P + 1) * sizeof(int);
    int* cntS = (int*)(ws + off);             off += (size_t)(P + 1) * sizeof(int);
    int* startD = (int*)(ws + off);           off += (size_t)(P + 1) * sizeof(int);
    int* startS = (int*)(ws + off);           off += (size_t)(P + 1) * sizeof(int);
    int* cursorD = (int*)(ws + off);          off += (size_t)(P + 1) * sizeof(int);
    int* cursorS = (int*)(ws + off);          off += (size_t)(P + 1) * sizeof(int);
    (void)ws_size;

    const int HB = 256;  // blocks for hist/scatter passes
    size_t lds_hist = 2u * P * sizeof(int);
    size_t lds_scat = 4u * P * sizeof(int);

    // zero the two count arrays (contiguous in ws) in one memset
    hipMemsetAsync(cntD, 0, 2u * (P + 1) * sizeof(int), stream);

    coarse_hist_kernel<<<HB, 256, lds_hist, stream>>>(src, dst, cntD, cntS, E, P);
    scan_kernel<<<1, 1024, 0, stream>>>(cntD, cntS, startD, cursorD, startS, cursorS, P);
    coarse_scatter_kernel<<<HB, 256, lds_scat, stream>>>(src, dst, cursorD, cursorS,
                                                         epart, spart, E, P);
    refine_kernel<<<P, 256, 0, stream>>>(epart, spart, startD, startS,
                                         csr, row_start, dis, N);

    int gLin = (N + ROWS_PB - 1) / ROWS_PB;
    linear_kernel<<<gLin, 256, 0, stream>>>(x, W, b, dis, hs, N);

    int NP = (N + 1) / 2;            // node pairs
    int gGat = (NP + 3) / 4;         // 4 waves (pairs) per block
    gather_kernel<<<gGat, 256, 0, stream>>>(hs, dis, row_start, csr, out, N);
}